// Round 5
// baseline (363.778 us; speedup 1.0000x reference)
//
#include <hip/hip_runtime.h>
#include <hip/hip_cooperative_groups.h>
#include <stdint.h>

namespace cg = cooperative_groups;

// Problem constants
#define B_   128
#define C_   500
#define H_   16
#define P_   256      // 16*16 pixels per image
#define D_   192
#define C1O  300
#define H1   34
#define P1   (H1*H1)  // 1156
#define C2O  100
#define H2   36
#define P2   (H2*H2)  // 1296
#define C3O  3
#define H3   38
#define P3   (H3*H3)  // 1444
#define CROP 3
#define OW_  32
#define KTOP 30

#define NSCAN  1000                     // scan blocks: 4000 waves x 16 (b,c)-pairs = 64000
#define NL1B   16                       // l1/thr blocks (32 channels each)
#define NTABB  25                       // tab blocks (4 rows each, one per wave) + partial crop
#define NGRID  (NSCAN + NL1B + NTABB)   // 1041 blocks; x5/CU residency -> coop-safe
#define NPAIR  (B_ * C_)                // 64000

__device__ __forceinline__ float sgnf(float v){ return (v > 0.f) ? 1.f : ((v < 0.f) ? -1.f : 0.f); }

// tap-validity pattern for a position in a length-36 conv output coming from a
// length-34 input (k=3, stride=1 transposed conv).
__device__ __forceinline__ int pat36(int i){
  if (i == 0) return 0;       // {0}
  if (i == 1) return 1;       // {0,1}
  if (i <= 33) return 2;      // {0,1,2}
  if (i == 34) return 3;      // {1,2}
  return 4;                   // {2}
}

// =====================================================================
// k_all: single cooperative kernel.
//   mode 0: phase1 (blocks: scan/l1/tab) -> grid.sync -> phase2 (blocks 0..127 final)
//   mode 1: phase1 only (ordinary-launch fallback)
//   mode 2: phase2 only (ordinary-launch fallback, grid = 128)
// Phase arithmetic is byte-identical to the round-4 k_pre / k_final pair.
// __launch_bounds__(256,5): 5 blocks/CU guaranteed -> 1280 >= 1041 co-resident.
// =====================================================================
__global__ __launch_bounds__(256, 5) void k_all(
    const float* __restrict__ x, const float* __restrict__ phi,
    const float* __restrict__ jumpp, const float* __restrict__ b1,
    const float* __restrict__ w2, const float* __restrict__ b2,
    const float* __restrict__ w3, const float* __restrict__ b3v,
    const float* __restrict__ w1,
    float* __restrict__ l1, float* __restrict__ thr,
    float* __restrict__ tab, float* __restrict__ part,
    float* __restrict__ M,
    signed char* __restrict__ zq, float* __restrict__ u1,
    float* __restrict__ u2, float* __restrict__ out,
    int have, int mode){
  const int blk = blockIdx.x;
  const int t = threadIdx.x;   // 256
  const int wave = t >> 6, lane = t & 63;

  // --- shared memory (union of both phases; 7.6 KB) ---
  __shared__ float redf[8][32];
  __shared__ float S4[4][9];
  __shared__ float tabR[4][25];
  __shared__ float w3s4[4][27];
  __shared__ unsigned char hot[P_];
  __shared__ unsigned char um[256];
  __shared__ unsigned char d1s[P1];
  __shared__ unsigned char d2s[P2];
  __shared__ int s_any;
  __shared__ float sx[C_];
  __shared__ unsigned char rm[C_];
  __shared__ unsigned long long redu[4];
  __shared__ int sel[KTOP];

  if (mode != 2){
    // =================== PHASE 1 ===================
    if (blk < NSCAN){
      // ------- scan: wave g owns pairs [16g, 16g+16) -------
      const int g = blk * 4 + wave;          // 0..3999
      const float* xg = x + (size_t)g * 16 * P_ + lane * 4;
#pragma unroll
      for (int j0 = 0; j0 < 16; j0 += 4){
        float4 v0 = *(const float4*)(xg + (size_t)(j0 + 0) * P_);
        float4 v1 = *(const float4*)(xg + (size_t)(j0 + 1) * P_);
        float4 v2 = *(const float4*)(xg + (size_t)(j0 + 2) * P_);
        float4 v3 = *(const float4*)(xg + (size_t)(j0 + 3) * P_);
        float m0 = fmaxf(fmaxf(fabsf(v0.x), fabsf(v0.y)), fmaxf(fabsf(v0.z), fabsf(v0.w)));
        float m1 = fmaxf(fmaxf(fabsf(v1.x), fabsf(v1.y)), fmaxf(fabsf(v1.z), fabsf(v1.w)));
        float m2 = fmaxf(fmaxf(fabsf(v2.x), fabsf(v2.y)), fmaxf(fabsf(v2.z), fabsf(v2.w)));
        float m3 = fmaxf(fmaxf(fabsf(v3.x), fabsf(v3.y)), fmaxf(fabsf(v3.z), fabsf(v3.w)));
#pragma unroll
        for (int off = 32; off; off >>= 1){
          m0 = fmaxf(m0, __shfl_down(m0, off));
          m1 = fmaxf(m1, __shfl_down(m1, off));
          m2 = fmaxf(m2, __shfl_down(m2, off));
          m3 = fmaxf(m3, __shfl_down(m3, off));
        }
        if (lane == 0)
          *(float4*)(M + g * 16 + j0) = make_float4(m0, m1, m2, m3);
      }
    } else if (blk < NSCAN + NL1B){
      // ------- l1 / thr: 32 channels, 8 d-groups -------
      const int bb = blk - NSCAN;
      const int cl = t & 31, dg = t >> 5;
      const int c = bb * 32 + cl;
      float s = 0.f;
      if (c < C_){
        const int d0 = dg * 24;
#pragma unroll 4
        for (int d = d0; d < d0 + 24; ++d) s += fabsf(phi[d * C_ + c]);
      }
      redf[dg][cl] = s;
      __syncthreads();
      if (t < 32){
        int cc = bb * 32 + t;
        if (cc < C_){
          float sum = 1e-12f;
#pragma unroll
          for (int g = 0; g < 8; ++g) sum += redf[g][t];
          l1[cc] = sum;
          thr[cc] = jumpp[0] * sum;
        }
      }
    } else {
      // ------- tab rows + partial base3 crop (block k owns c2 rows 4k..4k+3) -------
      const int k = blk - (NSCAN + NL1B);     // 0..24
      const int o = k * 4 + wave;             // 0..99
      for (int i = t; i < 4 * 27; i += 256)
        w3s4[i / 27][i % 27] = w3[(k * 4 + i / 27) * 27 + i % 27];
      {
        float acc[9] = {0,0,0,0,0,0,0,0,0};
        for (int c1 = lane; c1 < C1O; c1 += 64){
          float a1 = fmaxf(b1[c1], 0.f);
          const float* w = w2 + (c1 * C2O + o) * 9;
#pragma unroll
          for (int tap = 0; tap < 9; ++tap) acc[tap] += w[tap] * a1;
        }
#pragma unroll
        for (int tap = 0; tap < 9; ++tap)
          for (int off = 32; off; off >>= 1) acc[tap] += __shfl_down(acc[tap], off);
        if (lane == 0){
#pragma unroll
          for (int tap = 0; tap < 9; ++tap) S4[wave][tap] = acc[tap];
        }
      }
      __syncthreads();
      if (lane < 25){
        const int lo5[5] = {0,0,0,1,2}, hi5[5] = {0,1,2,2,2};
        int pr = lane / 5, pc = lane % 5;
        float s = b2[o];
        for (int kh = lo5[pr]; kh <= hi5[pr]; ++kh)
          for (int kw = lo5[pc]; kw <= hi5[pc]; ++kw) s += S4[wave][kh * 3 + kw];
        tab[o * 25 + lane] = s;
        tabR[wave][lane] = s;
      }
      __syncthreads();
      // partial crop: 1024 positions, 4 per thread, over this block's 4 c2 rows
      for (int pp = 0; pp < 4; ++pp){
        const int pos = pp * 256 + t;           // 0..1023
        const int r = pos >> 5, cc = pos & 31;
        const int oh = r + CROP, ow = cc + CROP;
        int ph[3], pw[3];
#pragma unroll
        for (int kk = 0; kk < 3; ++kk){ ph[kk] = pat36(oh - kk); pw[kk] = pat36(ow - kk); }
        float a0 = 0.f, a1v = 0.f, a2v = 0.f;
#pragma unroll
        for (int j = 0; j < 4; ++j){
          const float* tc = tabR[j];
          const float* wc = w3s4[j];
#pragma unroll
          for (int kh = 0; kh < 3; ++kh){
            const int prr = ph[kh] * 5;
#pragma unroll
            for (int kw = 0; kw < 3; ++kw){
              float a2 = fmaxf(tc[prr + pw[kw]], 0.f);
              a0  += wc[0 * 9 + kh * 3 + kw] * a2;
              a1v += wc[1 * 9 + kh * 3 + kw] * a2;
              a2v += wc[2 * 9 + kh * 3 + kw] * a2;
            }
          }
        }
        part[(k * 3 + 0) * 1024 + pos] = a0;
        part[(k * 3 + 1) * 1024 + pos] = a1v;
        part[(k * 3 + 2) * 1024 + pos] = a2v;
      }
    }
  }

  if (mode == 0){
    __threadfence();
    cg::this_grid().sync();
  }
  if (mode == 1) return;

  // =================== PHASE 2 (blocks 0..127) ===================
  const int b = blk;
  if (b >= B_) return;

  if (t == 0) s_any = 0;
  __syncthreads();
  for (int c = t; c < C_; c += 256)
    if (M[b * C_ + c] >= thr[c]) s_any = 1;     // benign race
  __syncthreads();

  if (!s_any){
    // -------- clean path: out = relu(b3 + sum_k part[k]), float4 stores --------
    for (int i = t; i < 3 * OW_ * (OW_ / 4); i += 256){   // 768
      int o = i >> 8, rr = i & 255;
      int r = rr >> 3, q4 = rr & 7;
      int pos = r * 32 + q4 * 4;
      float bv = b3v[o];
      float4 s = make_float4(bv, bv, bv, bv);
      for (int k = 0; k < NTABB; ++k){
        const float4 v = *(const float4*)(part + ((size_t)(k * 3 + o) << 10) + pos);
        s.x += v.x; s.y += v.y; s.z += v.z; s.w += v.w;
      }
      float4 res;
      res.x = fmaxf(s.x, 0.f);
      res.y = fmaxf(s.y, 0.f);
      res.z = fmaxf(s.z, 0.f);
      res.w = fmaxf(s.w, 0.f);
      *(float4*)(out + ((size_t)(b * 3 + o) * OW_ + r) * OW_ + q4 * 4) = res;
    }
    return;
  }
  if (!have) return;   // workspace too small for dirty path (never for bench)

  // -------- rebuild per-pixel hot flags (identical comparisons) --------
  {
    const int q = t & 15, cg2 = t >> 4;
    for (int tile = 0; tile < 4; ++tile){
      unsigned m = 0;
      const int pbase = tile * 64 + 4 * q;
      for (int c = cg2; c < C_; c += 16){
        float tc = thr[c];
        const float4 v = *(const float4*)(x + ((size_t)(b * C_ + c)) * P_ + pbase);
        if (fabsf(v.x) >= tc) m |= 1u;
        if (fabsf(v.y) >= tc) m |= 2u;
        if (fabsf(v.z) >= tc) m |= 4u;
        if (fabsf(v.w) >= tc) m |= 8u;
      }
      um[t] = (unsigned char)m;
      __syncthreads();
      if (t < 64){
        const int qq = t >> 2, j = t & 3;
        unsigned mm = 0;
#pragma unroll
        for (int g = 0; g < 16; ++g) mm |= um[g * 16 + qq];
        hot[tile * 64 + t] = (unsigned char)((mm >> j) & 1u);
      }
      __syncthreads();
    }
  }

  const float J = jumpp[0];

  // -------- stage A: exact top-30 + quant codes for each hot pixel --------
  for (int px = 0; px < P_; ++px){
    if (!hot[px]) continue;
    for (int c = t; c < C_; c += 256){ sx[c] = x[(b * C_ + c) * P_ + px]; rm[c] = 0; }
    __syncthreads();
    for (int it = 0; it < KTOP; ++it){
      unsigned long long best = 0ULL;
      for (int c = t; c < C_; c += 256){
        if (!rm[c]){
          unsigned long long key =
            ((unsigned long long)__float_as_uint(fabsf(sx[c])) << 32) |
            (unsigned int)(C_ - 1 - c);          // ties -> lower index wins
          if (key > best) best = key;
        }
      }
      for (int off = 32; off; off >>= 1){
        unsigned long long o2 = __shfl_down(best, off);
        if (o2 > best) best = o2;
      }
      if ((t & 63) == 0) redu[t >> 6] = best;
      __syncthreads();
      if (t == 0){
        unsigned long long mx = redu[0];
        for (int wv = 1; wv < 4; ++wv) if (redu[wv] > mx) mx = redu[wv];
        int idx = C_ - 1 - (int)(mx & 0xffffffffULL);
        sel[it] = idx;
        rm[idx] = 1;
      }
      __syncthreads();
    }
    for (int c = t; c < C_; c += 256) zq[(b * C_ + c) * P_ + px] = 0;
    __syncthreads();
    if (t < KTOP){
      int c = sel[t];
      float r = sx[c] / l1[c];
      float qv = 0.5f * (sgnf(r - J) + sgnf(r + J));  // {-1,-0.5,0,0.5,1}
      int code = (int)(2.f * qv);                     // {-2,-1,0,1,2}
      if (code) zq[(b * C_ + c) * P_ + px] = (signed char)code;
    }
    __syncthreads();
  }

  // -------- stage B: d1 flags --------
  for (int p1 = t; p1 < P1; p1 += 256){
    int ih = p1 / H1, iw = p1 - (p1 / H1) * H1;
    int h0 = max(0, (ih - 2) >> 1), h1v = min(H_ - 1, ih >> 1);
    int w0 = max(0, (iw - 2) >> 1), w1v = min(H_ - 1, iw >> 1);
    int any = 0;
    for (int h = h0; h <= h1v; ++h)
      for (int w = w0; w <= w1v; ++w)
        any |= hot[h * H_ + w];
    d1s[p1] = (unsigned char)(any != 0);
  }
  __syncthreads();

  // -------- stage D: d2 flags --------
  for (int p2 = t; p2 < P2; p2 += 256){
    int oh = p2 / H2, ow = p2 - (p2 / H2) * H2;
    int any = 0;
    for (int kh = 0; kh < 3; ++kh){
      int ih = oh - kh; if (ih < 0 || ih >= H1) continue;
      for (int kw = 0; kw < 3; ++kw){
        int iw = ow - kw; if (iw < 0 || iw >= H1) continue;
        any |= d1s[ih * H1 + iw];
      }
    }
    d2s[p2] = (unsigned char)(any != 0);
  }
  __syncthreads();

  // -------- stage C: u1 at dirty-1 pixels (waves split pixels) --------
  for (int p1 = wave; p1 < P1; p1 += 4){
    if (!d1s[p1]) continue;
    int ih = p1 / H1, iw = p1 - (p1 / H1) * H1;
    float acc[5] = {0,0,0,0,0};
    int h0 = max(0, (ih - 2) >> 1), h1v = min(H_ - 1, ih >> 1);
    int w0 = max(0, (iw - 2) >> 1), w1v = min(H_ - 1, iw >> 1);
    for (int h = h0; h <= h1v; ++h)
      for (int w = w0; w <= w1v; ++w){
        if (!hot[h * H_ + w]) continue;
        int kh = ih - 2 * h, kw = iw - 2 * w;
        const signed char* zp = zq + (size_t)(b * C_) * P_ + h * H_ + w;
        for (int c = 0; c < C_; ++c){
          int code = zp[(size_t)c * P_];
          if (!code) continue;
          float val = 0.5f * (float)code * l1[c];
          const float* wp = w1 + (size_t)(c * C1O) * 16 + kh * 4 + kw;
#pragma unroll
          for (int j = 0; j < 5; ++j){
            int c1 = j * 64 + lane;
            if (c1 < C1O) acc[j] += wp[(size_t)c1 * 16] * val;
          }
        }
      }
#pragma unroll
    for (int j = 0; j < 5; ++j){
      int c1 = j * 64 + lane;
      if (c1 < C1O){
        float bb = b1[c1];
        u1[(size_t)(b * C1O + c1) * P1 + p1] = fmaxf(bb + acc[j], 0.f) - fmaxf(bb, 0.f);
      }
    }
  }
  __syncthreads();

  // -------- stage E: u2 at dirty-2 pixels --------
  for (int p2 = wave; p2 < P2; p2 += 4){
    if (!d2s[p2]) continue;
    int oh = p2 / H2, ow = p2 - (p2 / H2) * H2;
    float acc[2] = {0,0};
    for (int kh = 0; kh < 3; ++kh){
      int ih = oh - kh; if (ih < 0 || ih >= H1) continue;
      for (int kw = 0; kw < 3; ++kw){
        int iw = ow - kw; if (iw < 0 || iw >= H1) continue;
        if (!d1s[ih * H1 + iw]) continue;
        const float* up = u1 + (size_t)(b * C1O) * P1 + ih * H1 + iw;
        const float* wb = w2 + kh * 3 + kw;
        for (int c1 = 0; c1 < C1O; ++c1){
          float uv = up[(size_t)c1 * P1];
          if (uv == 0.f) continue;
          const float* wp = wb + (size_t)(c1 * C2O) * 9;
#pragma unroll
          for (int j = 0; j < 2; ++j){
            int c2 = j * 64 + lane;
            if (c2 < C2O) acc[j] += wp[(size_t)c2 * 9] * uv;
          }
        }
      }
    }
    int pr = pat36(oh) * 5 + pat36(ow);
#pragma unroll
    for (int j = 0; j < 2; ++j){
      int c2 = j * 64 + lane;
      if (c2 < C2O){
        float bs = tab[c2 * 25 + pr];
        u2[(size_t)(b * C2O + c2) * P2 + p2] = fmaxf(bs + acc[j], 0.f) - fmaxf(bs, 0.f);
      }
    }
  }
  __syncthreads();

  // -------- stage F: output --------
  for (int i = t; i < 3 * OW_ * OW_; i += 256){     // 3072
    int o = i >> 10, rc = i & 1023;
    int r = rc >> 5, cc = rc & 31;
    int oh = r + CROP, ow = cc + CROP;
    float acc = b3v[o];
    for (int k = 0; k < NTABB; ++k) acc += part[((size_t)(k * 3 + o) << 10) + rc];
    for (int kh = 0; kh < 3; ++kh){
      int ih = oh - kh;
      for (int kw = 0; kw < 3; ++kw){
        int iw = ow - kw;
        if (!d2s[ih * H2 + iw]) continue;
        const float* up = u2 + (size_t)(b * C2O) * P2 + ih * H2 + iw;
        const float* wp = w3 + o * 9 + kh * 3 + kw;
        for (int c2 = 0; c2 < C2O; ++c2){
          float uv = up[(size_t)c2 * P2];
          if (uv != 0.f) acc += wp[c2 * 27] * uv;
        }
      }
    }
    out[((size_t)(b * 3 + o) * OW_ + r) * OW_ + cc] = fmaxf(acc, 0.f);
  }
}

extern "C" void kernel_launch(void* const* d_in, const int* in_sizes, int n_in,
                              void* d_out, int out_size, void* d_ws, size_t ws_size,
                              hipStream_t stream){
  const float* x   = (const float*)d_in[0];
  const float* phi = (const float*)d_in[1];
  const float* jmp = (const float*)d_in[2];
  const float* w1  = (const float*)d_in[3];
  const float* b1  = (const float*)d_in[4];
  const float* w2  = (const float*)d_in[5];
  const float* b2  = (const float*)d_in[6];
  const float* w3  = (const float*)d_in[7];
  const float* b3  = (const float*)d_in[8];
  float* out = (float*)d_out;
  char* ws = (char*)d_ws;

  // workspace layout (bytes, 16B-aligned)
  constexpr size_t OFF_L1   = 0;                                  // 500 f32
  constexpr size_t OFF_THR  = OFF_L1   + 2048;
  constexpr size_t OFF_TAB  = OFF_THR  + 2048;                    // 2500 f32
  constexpr size_t OFF_PART = OFF_TAB  + 10240;                   // 25*3*1024 f32
  constexpr size_t OFF_M    = OFF_PART + (size_t)NTABB * 3 * 1024 * 4;  // 64000 f32
  constexpr size_t OFF_ZQ   = OFF_M    + (size_t)NPAIR * 4;       // i8 codes
  constexpr size_t OFF_U1   = OFF_ZQ   + (size_t)B_ * C_ * P_;
  constexpr size_t OFF_U2   = OFF_U1   + (size_t)B_ * C1O * P1 * 4;
  constexpr size_t TOTAL    = OFF_U2   + (size_t)B_ * C2O * P2 * 4;

  float* l1p  = (float*)(ws + OFF_L1);
  float* thrp = (float*)(ws + OFF_THR);
  float* tabp = (float*)(ws + OFF_TAB);
  float* prtp = (float*)(ws + OFF_PART);
  float* Mp   = (float*)(ws + OFF_M);
  signed char* zqp = (signed char*)(ws + OFF_ZQ);
  float* u1p = (float*)(ws + OFF_U1);
  float* u2p = (float*)(ws + OFF_U2);
  int have = (ws_size >= TOTAL) ? 1 : 0;

  int mode0 = 0;
  void* args[] = {
    (void*)&x, (void*)&phi, (void*)&jmp, (void*)&b1, (void*)&w2, (void*)&b2,
    (void*)&w3, (void*)&b3, (void*)&w1,
    (void*)&l1p, (void*)&thrp, (void*)&tabp, (void*)&prtp, (void*)&Mp,
    (void*)&zqp, (void*)&u1p, (void*)&u2p, (void*)&out,
    (void*)&have, (void*)&mode0
  };
  hipError_t e = hipLaunchCooperativeKernel((const void*)k_all, dim3(NGRID), dim3(256),
                                            args, 0, stream);
  if (e != hipSuccess){
    // fallback: proven two-launch path (phase1 then phase2 as ordinary kernels)
    hipLaunchKernelGGL(k_all, dim3(NGRID), dim3(256), 0, stream,
                       x, phi, jmp, b1, w2, b2, w3, b3, w1,
                       l1p, thrp, tabp, prtp, Mp, zqp, u1p, u2p, out, have, 1);
    hipLaunchKernelGGL(k_all, dim3(B_), dim3(256), 0, stream,
                       x, phi, jmp, b1, w2, b2, w3, b3, w1,
                       l1p, thrp, tabp, prtp, Mp, zqp, u1p, u2p, out, have, 2);
  }
}

// Round 6
// 118.196 us; speedup vs baseline: 3.0778x; 3.0778x over previous
//
#include <hip/hip_runtime.h>
#include <stdint.h>

// Problem constants
#define B_   128
#define C_   500
#define H_   16
#define P_   256      // 16*16 pixels per image
#define D_   192
#define C1O  300
#define H1   34
#define P1   (H1*H1)  // 1156
#define C2O  100
#define H2   36
#define P2   (H2*H2)  // 1296
#define C3O  3
#define H3   38
#define P3   (H3*H3)  // 1444
#define CROP 3
#define OW_  32
#define KTOP 30

#define NSCAN  1000                     // scan blocks: 4000 waves x 16 (b,c)-pairs = 64000
#define NL1B   16                       // l1/thr blocks (32 channels each)
#define NTABB  25                       // tab blocks (4 rows each, one per wave) + partial crop
#define NPAIR  (B_ * C_)                // 64000

__device__ __forceinline__ float sgnf(float v){ return (v > 0.f) ? 1.f : ((v < 0.f) ? -1.f : 0.f); }

// tap-validity pattern for a position in a length-36 conv output coming from a
// length-34 input (k=3, stride=1 transposed conv).
__device__ __forceinline__ int pat36(int i){
  if (i == 0) return 0;       // {0}
  if (i == 1) return 1;       // {0,1}
  if (i <= 33) return 2;      // {0,1,2}
  if (i == 34) return 3;      // {1,2}
  return 4;                   // {2}
}

// =====================================================================
// k_pre: ONE fused kernel, NO concentrated serial block (round-3 lesson:
// kernel duration = slowest block; never give one block 25x the work).
// Round-5 lesson: grid.sync() costs ~230us on MI355X (8 XCDs) -- a second
// kernel launch (~2-4us) is strictly cheaper. Keep two ordinary launches.
//   blocks 0..999     : streaming max-|x| per (b,c) pair -> M (BW long pole)
//   blocks 1000..1015 : l1 + thr (32 channels/block)
//   blocks 1016..1040 : tab rows o = k*4+wave (1 row/wave) + this block's
//                       4-channel partial of the base3 crop -> part[k][3][1024]
// =====================================================================
__global__ __launch_bounds__(256) void k_pre(
    const float* __restrict__ x, const float* __restrict__ phi,
    const float* __restrict__ jumpp, const float* __restrict__ b1,
    const float* __restrict__ w2, const float* __restrict__ b2,
    const float* __restrict__ w3,
    float* __restrict__ l1, float* __restrict__ thr,
    float* __restrict__ tab, float* __restrict__ part,
    float* __restrict__ M){
  const int blk = blockIdx.x;
  const int t = threadIdx.x;   // 256
  const int wave = t >> 6, lane = t & 63;

  if (blk < NSCAN){
    // ---------------- scan part: wave g owns pairs [16g, 16g+16) ----------------
    const int g = blk * 4 + wave;          // 0..3999
    const float* xg = x + (size_t)g * 16 * P_ + lane * 4;
#pragma unroll
    for (int j0 = 0; j0 < 16; j0 += 4){
      float4 v0 = *(const float4*)(xg + (size_t)(j0 + 0) * P_);
      float4 v1 = *(const float4*)(xg + (size_t)(j0 + 1) * P_);
      float4 v2 = *(const float4*)(xg + (size_t)(j0 + 2) * P_);
      float4 v3 = *(const float4*)(xg + (size_t)(j0 + 3) * P_);
      float m0 = fmaxf(fmaxf(fabsf(v0.x), fabsf(v0.y)), fmaxf(fabsf(v0.z), fabsf(v0.w)));
      float m1 = fmaxf(fmaxf(fabsf(v1.x), fabsf(v1.y)), fmaxf(fabsf(v1.z), fabsf(v1.w)));
      float m2 = fmaxf(fmaxf(fabsf(v2.x), fabsf(v2.y)), fmaxf(fabsf(v2.z), fabsf(v2.w)));
      float m3 = fmaxf(fmaxf(fabsf(v3.x), fabsf(v3.y)), fmaxf(fabsf(v3.z), fabsf(v3.w)));
#pragma unroll
      for (int off = 32; off; off >>= 1){
        m0 = fmaxf(m0, __shfl_down(m0, off));
        m1 = fmaxf(m1, __shfl_down(m1, off));
        m2 = fmaxf(m2, __shfl_down(m2, off));
        m3 = fmaxf(m3, __shfl_down(m3, off));
      }
      if (lane == 0)
        *(float4*)(M + g * 16 + j0) = make_float4(m0, m1, m2, m3);
    }
    return;
  }

  if (blk < NSCAN + NL1B){
    // ---------------- l1 / thr: 32 channels, 8 d-groups ----------------
    __shared__ float red[8][32];
    const int bb = blk - NSCAN;
    const int cl = t & 31, dg = t >> 5;
    const int c = bb * 32 + cl;
    float s = 0.f;
    if (c < C_){
      const int d0 = dg * 24;
#pragma unroll 4
      for (int d = d0; d < d0 + 24; ++d) s += fabsf(phi[d * C_ + c]);
    }
    red[dg][cl] = s;
    __syncthreads();
    if (t < 32){
      int cc = bb * 32 + t;
      if (cc < C_){
        float sum = 1e-12f;
#pragma unroll
        for (int g = 0; g < 8; ++g) sum += red[g][t];
        l1[cc] = sum;
        thr[cc] = jumpp[0] * sum;
      }
    }
    return;
  }

  // ---------------- tab rows + partial base3 crop ----------------
  // block k owns c2 rows {4k..4k+3}; wave handles row o = 4k+wave (round-1 layout)
  const int k = blk - (NSCAN + NL1B);     // 0..24
  const int o = k * 4 + wave;             // 0..99
  __shared__ float S[4][9];
  __shared__ float tabR[4][25];
  __shared__ float w3s[4][27];

  for (int i = t; i < 4 * 27; i += 256) w3s[i / 27][i % 27] = w3[(k * 4 + i / 27) * 27 + i % 27];

  {
    float acc[9] = {0,0,0,0,0,0,0,0,0};
    for (int c1 = lane; c1 < C1O; c1 += 64){
      float a1 = fmaxf(b1[c1], 0.f);
      const float* w = w2 + (c1 * C2O + o) * 9;
#pragma unroll
      for (int tap = 0; tap < 9; ++tap) acc[tap] += w[tap] * a1;
    }
#pragma unroll
    for (int tap = 0; tap < 9; ++tap)
      for (int off = 32; off; off >>= 1) acc[tap] += __shfl_down(acc[tap], off);
    if (lane == 0){
#pragma unroll
      for (int tap = 0; tap < 9; ++tap) S[wave][tap] = acc[tap];
    }
  }
  __syncthreads();

  if (lane < 25){
    const int lo5[5] = {0,0,0,1,2}, hi5[5] = {0,1,2,2,2};
    int pr = lane / 5, pc = lane % 5;
    float s = b2[o];
    for (int kh = lo5[pr]; kh <= hi5[pr]; ++kh)
      for (int kw = lo5[pc]; kw <= hi5[pc]; ++kw) s += S[wave][kh * 3 + kw];
    tab[o * 25 + lane] = s;
    tabR[wave][lane] = s;
  }
  __syncthreads();

  // partial crop: 1024 positions, 4 per thread; sum over this block's 4 c2 rows
  for (int pp = 0; pp < 4; ++pp){
    const int pos = pp * 256 + t;           // 0..1023
    const int r = pos >> 5, cc = pos & 31;
    const int oh = r + CROP, ow = cc + CROP;   // 3..34 -> all 9 taps valid
    int ph[3], pw[3];
#pragma unroll
    for (int kk = 0; kk < 3; ++kk){ ph[kk] = pat36(oh - kk); pw[kk] = pat36(ow - kk); }
    float a0 = 0.f, a1v = 0.f, a2v = 0.f;
#pragma unroll
    for (int j = 0; j < 4; ++j){
      const float* tc = tabR[j];
      const float* wc = w3s[j];
#pragma unroll
      for (int kh = 0; kh < 3; ++kh){
        const int prr = ph[kh] * 5;
#pragma unroll
        for (int kw = 0; kw < 3; ++kw){
          float a2 = fmaxf(tc[prr + pw[kw]], 0.f);
          a0  += wc[0 * 9 + kh * 3 + kw] * a2;
          a1v += wc[1 * 9 + kh * 3 + kw] * a2;
          a2v += wc[2 * 9 + kh * 3 + kw] * a2;
        }
      }
    }
    part[(k * 3 + 0) * 1024 + pos] = a0;
    part[(k * 3 + 1) * 1024 + pos] = a1v;
    part[(k * 3 + 2) * 1024 + pos] = a2v;
  }
}

// =====================================================================
// k_final: one block per image (256 threads). Image is dirty iff any
// channel has M[b,c] >= thr[c]. Clean -> out = relu(b3 + sum_k part[k]);
// dirty -> rebuild per-pixel hot flags in-block then the exact chain:
// topk/quant -> d1 -> u1 -> d2 -> u2 -> out (unchanged arithmetic).
// =====================================================================
__global__ void k_final(const float* __restrict__ x, const float* __restrict__ l1,
                        const float* __restrict__ jumpp, const float* __restrict__ tab,
                        const float* __restrict__ w1, const float* __restrict__ b1,
                        const float* __restrict__ w2, const float* __restrict__ w3,
                        const float* __restrict__ b3v,
                        const float* __restrict__ part, const float* __restrict__ M,
                        const float* __restrict__ thr,
                        signed char* __restrict__ zq, float* __restrict__ u1,
                        float* __restrict__ u2, float* __restrict__ out, int have){
  const int b = blockIdx.x;
  const int t = threadIdx.x;          // 256
  const int wave = t >> 6, lane = t & 63;

  __shared__ unsigned char hot[P_];
  __shared__ unsigned char um[256];
  __shared__ unsigned char d1s[P1];
  __shared__ unsigned char d2s[P2];
  __shared__ int s_any;
  __shared__ float sx[C_];
  __shared__ unsigned char rm[C_];
  __shared__ unsigned long long red[4];
  __shared__ int sel[KTOP];

  if (t == 0) s_any = 0;
  __syncthreads();
  for (int c = t; c < C_; c += 256)
    if (M[b * C_ + c] >= thr[c]) s_any = 1;     // benign race
  __syncthreads();

  if (!s_any){
    // -------- clean path: out = relu(b3 + sum_k part[k]), float4 stores --------
    for (int i = t; i < 3 * OW_ * (OW_ / 4); i += 256){   // 768
      int o = i >> 8, rr = i & 255;
      int r = rr >> 3, q4 = rr & 7;
      int pos = r * 32 + q4 * 4;
      float bv = b3v[o];
      float4 s = make_float4(bv, bv, bv, bv);
      for (int k = 0; k < NTABB; ++k){
        const float4 v = *(const float4*)(part + ((size_t)(k * 3 + o) << 10) + pos);
        s.x += v.x; s.y += v.y; s.z += v.z; s.w += v.w;
      }
      float4 res;
      res.x = fmaxf(s.x, 0.f);
      res.y = fmaxf(s.y, 0.f);
      res.z = fmaxf(s.z, 0.f);
      res.w = fmaxf(s.w, 0.f);
      *(float4*)(out + ((size_t)(b * 3 + o) * OW_ + r) * OW_ + q4 * 4) = res;
    }
    return;
  }
  if (!have) return;   // workspace too small for dirty path (never for bench)

  // -------- rebuild per-pixel hot flags (identical comparisons) --------
  {
    const int q = t & 15, cg = t >> 4;
    for (int tile = 0; tile < 4; ++tile){
      unsigned m = 0;
      const int pbase = tile * 64 + 4 * q;
      for (int c = cg; c < C_; c += 16){
        float tc = thr[c];
        const float4 v = *(const float4*)(x + ((size_t)(b * C_ + c)) * P_ + pbase);
        if (fabsf(v.x) >= tc) m |= 1u;
        if (fabsf(v.y) >= tc) m |= 2u;
        if (fabsf(v.z) >= tc) m |= 4u;
        if (fabsf(v.w) >= tc) m |= 8u;
      }
      um[t] = (unsigned char)m;
      __syncthreads();
      if (t < 64){
        const int qq = t >> 2, j = t & 3;
        unsigned mm = 0;
#pragma unroll
        for (int g = 0; g < 16; ++g) mm |= um[g * 16 + qq];
        hot[tile * 64 + t] = (unsigned char)((mm >> j) & 1u);
      }
      __syncthreads();
    }
  }

  const float J = jumpp[0];

  // -------- stage A: exact top-30 + quant codes for each hot pixel --------
  for (int px = 0; px < P_; ++px){
    if (!hot[px]) continue;
    for (int c = t; c < C_; c += 256){ sx[c] = x[(b * C_ + c) * P_ + px]; rm[c] = 0; }
    __syncthreads();
    for (int it = 0; it < KTOP; ++it){
      unsigned long long best = 0ULL;
      for (int c = t; c < C_; c += 256){
        if (!rm[c]){
          unsigned long long key =
            ((unsigned long long)__float_as_uint(fabsf(sx[c])) << 32) |
            (unsigned int)(C_ - 1 - c);          // ties -> lower index wins
          if (key > best) best = key;
        }
      }
      for (int off = 32; off; off >>= 1){
        unsigned long long o2 = __shfl_down(best, off);
        if (o2 > best) best = o2;
      }
      if ((t & 63) == 0) red[t >> 6] = best;
      __syncthreads();
      if (t == 0){
        unsigned long long mx = red[0];
        for (int wv = 1; wv < 4; ++wv) if (red[wv] > mx) mx = red[wv];
        int idx = C_ - 1 - (int)(mx & 0xffffffffULL);
        sel[it] = idx;
        rm[idx] = 1;
      }
      __syncthreads();
    }
    for (int c = t; c < C_; c += 256) zq[(b * C_ + c) * P_ + px] = 0;
    __syncthreads();
    if (t < KTOP){
      int c = sel[t];
      float r = sx[c] / l1[c];
      float qv = 0.5f * (sgnf(r - J) + sgnf(r + J));  // {-1,-0.5,0,0.5,1}
      int code = (int)(2.f * qv);                     // {-2,-1,0,1,2}
      if (code) zq[(b * C_ + c) * P_ + px] = (signed char)code;
    }
    __syncthreads();
  }

  // -------- stage B: d1 flags --------
  for (int p1 = t; p1 < P1; p1 += 256){
    int ih = p1 / H1, iw = p1 - (p1 / H1) * H1;
    int h0 = max(0, (ih - 2) >> 1), h1v = min(H_ - 1, ih >> 1);
    int w0 = max(0, (iw - 2) >> 1), w1v = min(H_ - 1, iw >> 1);
    int any = 0;
    for (int h = h0; h <= h1v; ++h)
      for (int w = w0; w <= w1v; ++w)
        any |= hot[h * H_ + w];
    d1s[p1] = (unsigned char)(any != 0);
  }
  __syncthreads();

  // -------- stage D: d2 flags --------
  for (int p2 = t; p2 < P2; p2 += 256){
    int oh = p2 / H2, ow = p2 - (p2 / H2) * H2;
    int any = 0;
    for (int kh = 0; kh < 3; ++kh){
      int ih = oh - kh; if (ih < 0 || ih >= H1) continue;
      for (int kw = 0; kw < 3; ++kw){
        int iw = ow - kw; if (iw < 0 || iw >= H1) continue;
        any |= d1s[ih * H1 + iw];
      }
    }
    d2s[p2] = (unsigned char)(any != 0);
  }
  __syncthreads();

  // -------- stage C: u1 at dirty-1 pixels (waves split pixels) --------
  for (int p1 = wave; p1 < P1; p1 += 4){
    if (!d1s[p1]) continue;
    int ih = p1 / H1, iw = p1 - (p1 / H1) * H1;
    float acc[5] = {0,0,0,0,0};
    int h0 = max(0, (ih - 2) >> 1), h1v = min(H_ - 1, ih >> 1);
    int w0 = max(0, (iw - 2) >> 1), w1v = min(H_ - 1, iw >> 1);
    for (int h = h0; h <= h1v; ++h)
      for (int w = w0; w <= w1v; ++w){
        if (!hot[h * H_ + w]) continue;
        int kh = ih - 2 * h, kw = iw - 2 * w;
        const signed char* zp = zq + (size_t)(b * C_) * P_ + h * H_ + w;
        for (int c = 0; c < C_; ++c){
          int code = zp[(size_t)c * P_];
          if (!code) continue;
          float val = 0.5f * (float)code * l1[c];
          const float* wp = w1 + (size_t)(c * C1O) * 16 + kh * 4 + kw;
#pragma unroll
          for (int j = 0; j < 5; ++j){
            int c1 = j * 64 + lane;
            if (c1 < C1O) acc[j] += wp[(size_t)c1 * 16] * val;
          }
        }
      }
#pragma unroll
    for (int j = 0; j < 5; ++j){
      int c1 = j * 64 + lane;
      if (c1 < C1O){
        float bb = b1[c1];
        u1[(size_t)(b * C1O + c1) * P1 + p1] = fmaxf(bb + acc[j], 0.f) - fmaxf(bb, 0.f);
      }
    }
  }
  __syncthreads();

  // -------- stage E: u2 at dirty-2 pixels --------
  for (int p2 = wave; p2 < P2; p2 += 4){
    if (!d2s[p2]) continue;
    int oh = p2 / H2, ow = p2 - (p2 / H2) * H2;
    float acc[2] = {0,0};
    for (int kh = 0; kh < 3; ++kh){
      int ih = oh - kh; if (ih < 0 || ih >= H1) continue;
      for (int kw = 0; kw < 3; ++kw){
        int iw = ow - kw; if (iw < 0 || iw >= H1) continue;
        if (!d1s[ih * H1 + iw]) continue;
        const float* up = u1 + (size_t)(b * C1O) * P1 + ih * H1 + iw;
        const float* wb = w2 + kh * 3 + kw;
        for (int c1 = 0; c1 < C1O; ++c1){
          float uv = up[(size_t)c1 * P1];
          if (uv == 0.f) continue;
          const float* wp = wb + (size_t)(c1 * C2O) * 9;
#pragma unroll
          for (int j = 0; j < 2; ++j){
            int c2 = j * 64 + lane;
            if (c2 < C2O) acc[j] += wp[(size_t)c2 * 9] * uv;
          }
        }
      }
    }
    int pr = pat36(oh) * 5 + pat36(ow);
#pragma unroll
    for (int j = 0; j < 2; ++j){
      int c2 = j * 64 + lane;
      if (c2 < C2O){
        float bs = tab[c2 * 25 + pr];
        u2[(size_t)(b * C2O + c2) * P2 + p2] = fmaxf(bs + acc[j], 0.f) - fmaxf(bs, 0.f);
      }
    }
  }
  __syncthreads();

  // -------- stage F: output --------
  for (int i = t; i < 3 * OW_ * OW_; i += 256){     // 3072
    int o = i >> 10, rc = i & 1023;
    int r = rc >> 5, cc = rc & 31;
    int oh = r + CROP, ow = cc + CROP;
    float acc = b3v[o];
    for (int k = 0; k < NTABB; ++k) acc += part[((size_t)(k * 3 + o) << 10) + rc];
    for (int kh = 0; kh < 3; ++kh){
      int ih = oh - kh;
      for (int kw = 0; kw < 3; ++kw){
        int iw = ow - kw;
        if (!d2s[ih * H2 + iw]) continue;
        const float* up = u2 + (size_t)(b * C2O) * P2 + ih * H2 + iw;
        const float* wp = w3 + o * 9 + kh * 3 + kw;
        for (int c2 = 0; c2 < C2O; ++c2){
          float uv = up[(size_t)c2 * P2];
          if (uv != 0.f) acc += wp[c2 * 27] * uv;
        }
      }
    }
    out[((size_t)(b * 3 + o) * OW_ + r) * OW_ + cc] = fmaxf(acc, 0.f);
  }
}

extern "C" void kernel_launch(void* const* d_in, const int* in_sizes, int n_in,
                              void* d_out, int out_size, void* d_ws, size_t ws_size,
                              hipStream_t stream){
  const float* x   = (const float*)d_in[0];
  const float* phi = (const float*)d_in[1];
  const float* jmp = (const float*)d_in[2];
  const float* w1  = (const float*)d_in[3];
  const float* b1  = (const float*)d_in[4];
  const float* w2  = (const float*)d_in[5];
  const float* b2  = (const float*)d_in[6];
  const float* w3  = (const float*)d_in[7];
  const float* b3  = (const float*)d_in[8];
  float* out = (float*)d_out;
  char* ws = (char*)d_ws;

  // workspace layout (bytes, 16B-aligned)
  constexpr size_t OFF_L1   = 0;                                  // 500 f32
  constexpr size_t OFF_THR  = OFF_L1   + 2048;
  constexpr size_t OFF_TAB  = OFF_THR  + 2048;                    // 2500 f32
  constexpr size_t OFF_PART = OFF_TAB  + 10240;                   // 25*3*1024 f32
  constexpr size_t OFF_M    = OFF_PART + (size_t)NTABB * 3 * 1024 * 4;  // 64000 f32
  constexpr size_t OFF_ZQ   = OFF_M    + (size_t)NPAIR * 4;       // i8 codes
  constexpr size_t OFF_U1   = OFF_ZQ   + (size_t)B_ * C_ * P_;
  constexpr size_t OFF_U2   = OFF_U1   + (size_t)B_ * C1O * P1 * 4;
  constexpr size_t TOTAL    = OFF_U2   + (size_t)B_ * C2O * P2 * 4;

  float* l1p  = (float*)(ws + OFF_L1);
  float* thrp = (float*)(ws + OFF_THR);
  float* tabp = (float*)(ws + OFF_TAB);
  float* prtp = (float*)(ws + OFF_PART);
  float* Mp   = (float*)(ws + OFF_M);
  signed char* zqp = (signed char*)(ws + OFF_ZQ);
  float* u1p = (float*)(ws + OFF_U1);
  float* u2p = (float*)(ws + OFF_U2);
  int have = (ws_size >= TOTAL) ? 1 : 0;

  k_pre  <<<NSCAN + NL1B + NTABB, 256, 0, stream>>>(x, phi, jmp, b1, w2, b2, w3,
                                                    l1p, thrp, tabp, prtp, Mp);
  k_final<<<B_, 256, 0, stream>>>(x, l1p, jmp, tabp, w1, b1, w2, w3, b3,
                                  prtp, Mp, thrp, zqp, u1p, u2p, out, have);
}